// Round 5
// baseline (547.310 us; speedup 1.0000x reference)
//
#include <hip/hip_runtime.h>

// HierarchicalRouter: 32768 tokens x D=2048 fp32.
// Outputs (concat in d_out): final_weights [32768,2], dispatch_mask [32768,64], router_loss [1].
// R1/R3 lesson: per-lane state > ~84 VGPRs spills (compiler is occupancy-greedy). R2 lesson:
// per-chunk LDS staging barriers drain the pipe. R4 lesson: lane-over-d makes weights
// lane-varying -> 2.6 GB redundant VMEM weight traffic + too few VGPRs for MLP => 260 us
// latency-bound at 7% HBM / 31% VALU.
// R5: lane = TOKEN. Weight addresses become wave-uniform -> scalar pipe (s_load / constant
// cache), zero VMEM weight traffic. Block = 512 thr = 8 waves; wave w covers D-slice
// [w*256, w*256+256) for 64 tokens; acc[20] partials per lane; one barrier; wave 0 reduces
// 8 partials from LDS (stride 21, conflict-free) and does the epilogue per-lane in parallel.
// Vector pipe carries only x (64 imm-offset dwordx4 per wave, 256 MB total, read once).

#define NTOK    32768
#define DIM     2048
#define NG      16      // router groups (rows of Wg)
#define GS      4       // experts per group (rows of We)
#define NE      64      // total experts
#define NR      20      // NG + GS stacked weight rows
#define NW      8       // waves per block = D-slices
#define SLICE   (DIM / NW)   // 256 floats per wave slice
#define TPB     (NW * 64)    // 512 threads
#define PAD     21      // padded partial stride (21 coprime 32 -> conflict-free)
#define NSHADOW 32      // shadow copies of expert_load to spread atomic contention

__global__ __launch_bounds__(TPB, 2) void router_main(
    const float* __restrict__ x,
    const float* __restrict__ Wg,
    const float* __restrict__ We,
    float* __restrict__ fw_out,
    float* __restrict__ dm_out,
    float* __restrict__ ws)
{
    __shared__ float part[NW * 64 * PAD];  // 43 KB partial logits
    __shared__ float lds_load[NE];         // per-block expert load (wave 0 only)

    const int tid  = threadIdx.x;
    const int lane = tid & 63;
    const int wv   = __builtin_amdgcn_readfirstlane(tid >> 6);  // d-slice, wave-uniform
    const long tok = (long)blockIdx.x * 64 + lane;              // this lane's token

    // lane's x pointer: token row + slice offset; all 64 q-loads are imm offsets off this
    const float* xp = x  + (size_t)tok * DIM + wv * SLICE;
    const float* wg = Wg + wv * SLICE;   // row r at wg + r*DIM (uniform address -> s_load)
    const float* we = We + wv * SLICE;

    float acc[NR];
    #pragma unroll
    for (int r = 0; r < NR; ++r) acc[r] = 0.0f;

    #pragma unroll 4
    for (int q = 0; q < SLICE / 4; ++q) {    // 64 quads
        float4 xv = *(const float4*)(xp + q * 4);
        #pragma unroll
        for (int r = 0; r < NG; ++r) {
            float4 w4 = *(const float4*)(wg + (size_t)r * DIM + q * 4);  // wave-uniform
            acc[r] += xv.x * w4.x + xv.y * w4.y + xv.z * w4.z + xv.w * w4.w;
        }
        #pragma unroll
        for (int r = 0; r < GS; ++r) {
            float4 w4 = *(const float4*)(we + (size_t)r * DIM + q * 4);  // wave-uniform
            acc[NG + r] += xv.x * w4.x + xv.y * w4.y + xv.z * w4.z + xv.w * w4.w;
        }
    }

    // publish partials: lane-stride PAD=21 words -> all 32 banks, conflict-free
    #pragma unroll
    for (int r = 0; r < NR; ++r) part[(wv * 64 + lane) * PAD + r] = acc[r];
    __syncthreads();

    if (tid < 64) {   // wave 0: per-lane = per-token epilogue, fully parallel
        float lg[NR];
        #pragma unroll
        for (int r = 0; r < NR; ++r) lg[r] = 0.0f;
        #pragma unroll
        for (int w = 0; w < NW; ++w)
            #pragma unroll
            for (int r = 0; r < NR; ++r)
                lg[r] += part[(w * 64 + lane) * PAD + r];

        // group softmax + top-1 (strict > on exp values = first-index-wins, matches np)
        float m16 = lg[0];
        #pragma unroll
        for (int r = 1; r < NG; ++r) m16 = fmaxf(m16, lg[r]);
        float den = 0.0f, bm = -1.0f; int gi = 0;
        #pragma unroll
        for (int r = 0; r < NG; ++r) {
            float e = expf(lg[r] - m16);
            den += e;
            if (e > bm) { bm = e; gi = r; }
        }
        float gw = bm / den;

        // local softmax (4) + top-2
        float m4 = fmaxf(fmaxf(lg[NG + 0], lg[NG + 1]), fmaxf(lg[NG + 2], lg[NG + 3]));
        float pr[GS]; float s4 = 0.0f;
        #pragma unroll
        for (int r = 0; r < GS; ++r) { pr[r] = expf(lg[NG + r] - m4); s4 += pr[r]; }
        float inv4 = 1.0f / s4;
        #pragma unroll
        for (int r = 0; r < GS; ++r) pr[r] *= inv4;

        int i0 = 0; float v0 = pr[0];
        #pragma unroll
        for (int r = 1; r < GS; ++r) if (pr[r] > v0) { v0 = pr[r]; i0 = r; }
        int i1 = -1; float v1 = -1.0f;
        #pragma unroll
        for (int r = 0; r < GS; ++r) if (r != i0 && pr[r] > v1) { v1 = pr[r]; i1 = r; }

        float nrm = v0 + v1 + 1e-7f;
        float sf0 = gw * (v0 / nrm);
        float sf1 = gw * (v1 / nrm);
        int   se0 = (gi << 2) + i0;
        int   se1 = (gi << 2) + i1;

        float sg = 0.0f;
        #pragma unroll
        for (int r = 0; r < NG; ++r) sg += lg[r] * lg[r];
        float sl = 0.0f;
        #pragma unroll
        for (int r = 0; r < GS; ++r) sl += lg[NG + r] * lg[NG + r];
        float sz = sg * (1.0f / 16.0f) + sl * 0.25f;   // per-token z contribution

        // dispatch-mask row (64 floats, 16 float4 stores; ~8.4 MB total - trivial traffic)
        float* dmrow = dm_out + (size_t)tok * NE;
        #pragma unroll
        for (int j = 0; j < 16; ++j) {
            int c = j * 4;
            float4 v;
            v.x = (c + 0 == se0) ? sf0 : (c + 0 == se1) ? sf1 : 0.0f;
            v.y = (c + 1 == se0) ? sf0 : (c + 1 == se1) ? sf1 : 0.0f;
            v.z = (c + 2 == se0) ? sf0 : (c + 2 == se1) ? sf1 : 0.0f;
            v.w = (c + 3 == se0) ? sf0 : (c + 3 == se1) ? sf1 : 0.0f;
            *(float4*)(dmrow + c) = v;
        }
        *(float2*)(fw_out + tok * 2) = make_float2(sf0, sf1);  // lanes contiguous

        // expert load: wave-0-private LDS accumulator (in-wave program order, no barrier)
        lds_load[lane] = 0.0f;
        atomicAdd(&lds_load[se0], sf0);
        atomicAdd(&lds_load[se1], sf1);
        atomicAdd(&ws[(blockIdx.x & (NSHADOW - 1)) * NE + lane], lds_load[lane]);

        // z-loss: butterfly over the wave, one global atomic
        #pragma unroll
        for (int s = 32; s > 0; s >>= 1) sz += __shfl_xor(sz, s, 64);
        if (lane == 0) atomicAdd(&ws[NSHADOW * NE], sz);
    }
}

__global__ void router_finalize(const float* __restrict__ ws, float* __restrict__ out_loss)
{
    int e = threadIdx.x;  // 64 threads = 1 wave
    float load = 0.0f;
    #pragma unroll
    for (int s = 0; s < NSHADOW; ++s) load += ws[s * NE + e];
    float tot = load;
    #pragma unroll
    for (int s = 32; s > 0; s >>= 1) tot += __shfl_xor(tot, s, 64);
    float target = tot * (1.0f / NE);
    float dev = load - target;
    float sq = dev * dev;
    #pragma unroll
    for (int s = 32; s > 0; s >>= 1) sq += __shfl_xor(sq, s, 64);
    if (e == 0) {
        float lb = sq * (1.0f / NE);
        float z  = ws[NSHADOW * NE] * (1.0f / NTOK);
        out_loss[0] = 0.001f * (lb + z);
    }
}

extern "C" void kernel_launch(void* const* d_in, const int* in_sizes, int n_in,
                              void* d_out, int out_size, void* d_ws, size_t ws_size,
                              hipStream_t stream)
{
    const float* x  = (const float*)d_in[0];
    const float* Wg = (const float*)d_in[1];
    const float* We = (const float*)d_in[2];
    float* out = (float*)d_out;
    float* fw  = out;                                         // [32768, 2]
    float* dm  = out + (size_t)NTOK * 2;                      // [32768, 64]
    float* ls  = out + (size_t)NTOK * 2 + (size_t)NTOK * NE;  // [1]
    float* ws  = (float*)d_ws;

    hipMemsetAsync(ws, 0, (NSHADOW * NE + 1) * sizeof(float), stream);
    router_main<<<NTOK / 64, TPB, 0, stream>>>(x, Wg, We, fw, dm, ws);
    router_finalize<<<1, 64, 0, stream>>>(ws, ls);
}